// Round 4
// baseline (150.817 us; speedup 1.0000x reference)
//
#include <hip/hip_runtime.h>
#include <hip/hip_bf16.h>

// out[m,n] = sum_k x[m,k] * W[1023-n,k] + b[1023-n]
// M=32768, N=256, K=512; fp32 in/out; bf16 MFMA.
// Barrier-free streaming GEMM: no LDS, no __syncthreads.
//  - prepass: W_sel -> bf16 Bmat[256][512] (n-major) in d_ws (256 KiB, L2-resident)
//  - gemm: A-frags loaded direct from x in MFMA fragment layout (16 rows x 128B runs,
//    L1 absorbs the 4x intra-block reuse); B-frags direct from Bmat; 2-deep SW pipeline.

#define M_TOT 32768
#define K_TOT 512
#define N_TOT 256
#define W_LD  1024

#define NTH 256              /* 4 waves per block */
#define ROWS_PER_BLK 32      /* 2 m-frags of 16 */

typedef __bf16 bf16x8 __attribute__((ext_vector_type(8)));
typedef float  f32x4  __attribute__((ext_vector_type(4)));

static __device__ __forceinline__ bf16x8 cvt8(f32x4 a, f32x4 b) {
    bf16x8 r;
    r[0] = (__bf16)a[0]; r[1] = (__bf16)a[1]; r[2] = (__bf16)a[2]; r[3] = (__bf16)a[3];
    r[4] = (__bf16)b[0]; r[5] = (__bf16)b[1]; r[6] = (__bf16)b[2]; r[7] = (__bf16)b[3];
    return r;
}

// ---- prepass: Bmat[n][k] = bf16(W[1023-n][k]), n<256, k<512 ----
__global__ __launch_bounds__(256)
void ng_prep(const float* __restrict__ W, __bf16* __restrict__ Bm)
{
    const int id = blockIdx.x * 256 + threadIdx.x;   // 16384 units: n(256) x kg(64)
    const int n  = id >> 6;
    const int kg = id & 63;
    const float* src = W + (long)(1023 - n) * W_LD + kg * 8;
    f32x4 a = *(const f32x4*)src;
    f32x4 b = *(const f32x4*)(src + 4);
    *(bf16x8*)(Bm + n * K_TOT + kg * 8) = cvt8(a, b);
}

__global__ __launch_bounds__(NTH, 4)
void ng_gemm(const float* __restrict__ x, const __bf16* __restrict__ Bm,
             const float* __restrict__ bias, float* __restrict__ out)
{
    const int lane = threadIdx.x & 63;
    const int wcol = threadIdx.x >> 6;      // 0..3 : 64 output cols each
    const long mBase = (long)blockIdx.x * ROWS_PER_BLK;

    const int r16 = lane & 15;              // row/col within frag
    const int ko  = lane >> 4;              // k-octet 0..3

    // A: lane reads x[mBase + mi*16 + r16][kk*32 + ko*8 .. +7]  (32B contiguous)
    const float* pa0 = x + (mBase + r16) * K_TOT + ko * 8;
    const float* pa1 = pa0 + 16 * K_TOT;
    // B: lane reads Bmat[wcol*64 + ni*16 + r16][kk*32 + ko*8 .. +7] (16B contiguous)
    const __bf16* pb0 = Bm + (wcol * 64 + r16) * K_TOT + ko * 8;
    const __bf16* pb1 = pb0 + 16 * K_TOT;
    const __bf16* pb2 = pb0 + 32 * K_TOT;
    const __bf16* pb3 = pb0 + 48 * K_TOT;

    f32x4 acc[2][4];
#pragma unroll
    for (int mi = 0; mi < 2; ++mi)
#pragma unroll
        for (int ni = 0; ni < 4; ++ni)
            acc[mi][ni] = (f32x4){0.f, 0.f, 0.f, 0.f};

    // two named pipeline sets (static indexing only — rule #20)
    f32x4  aE[2][2], aO[2][2];
    bf16x8 bE[4], bO[4];

#define LDSET(AA_, BB_, kk_) do {                                   \
        AA_[0][0] = *(const f32x4*)(pa0 + (kk_) * 32);              \
        AA_[0][1] = *(const f32x4*)(pa0 + (kk_) * 32 + 4);          \
        AA_[1][0] = *(const f32x4*)(pa1 + (kk_) * 32);              \
        AA_[1][1] = *(const f32x4*)(pa1 + (kk_) * 32 + 4);          \
        BB_[0] = *(const bf16x8*)(pb0 + (kk_) * 32);                \
        BB_[1] = *(const bf16x8*)(pb1 + (kk_) * 32);                \
        BB_[2] = *(const bf16x8*)(pb2 + (kk_) * 32);                \
        BB_[3] = *(const bf16x8*)(pb3 + (kk_) * 32);                \
    } while (0)

#define MMA(AA_, BB_) do {                                                        \
        bf16x8 a0_ = cvt8(AA_[0][0], AA_[0][1]);                                  \
        bf16x8 a1_ = cvt8(AA_[1][0], AA_[1][1]);                                  \
        _Pragma("unroll")                                                         \
        for (int ni_ = 0; ni_ < 4; ++ni_) {                                       \
            acc[0][ni_] = __builtin_amdgcn_mfma_f32_16x16x32_bf16(                \
                a0_, BB_[ni_], acc[0][ni_], 0, 0, 0);                             \
            acc[1][ni_] = __builtin_amdgcn_mfma_f32_16x16x32_bf16(                \
                a1_, BB_[ni_], acc[1][ni_], 0, 0, 0);                             \
        }                                                                         \
    } while (0)

    LDSET(aE, bE, 0);
#pragma unroll
    for (int kk = 0; kk < 16; kk += 2) {
        if (kk + 1 < 16) LDSET(aO, bO, kk + 1);
        MMA(aE, bE);
        if (kk + 2 < 16) LDSET(aE, bE, kk + 2);
        MMA(aO, bO);
    }

    // ---- epilogue: C/D layout col=lane&15, row=(lane>>4)*4+i ; reversed bias ----
    const int cRow = (lane >> 4) * 4;
    const int cCol = wcol * 64 + (lane & 15);
#pragma unroll
    for (int ni = 0; ni < 4; ++ni) {
        const int gn = cCol + ni * 16;
        const float bv = bias[1023 - gn];
#pragma unroll
        for (int mi = 0; mi < 2; ++mi) {
            float* dst = out + (mBase + cRow + mi * 16) * (long)N_TOT + gn;
#pragma unroll
            for (int i = 0; i < 4; ++i)
                dst[(long)i * N_TOT] = acc[mi][ni][i] + bv;
        }
    }
#undef LDSET
#undef MMA
}

extern "C" void kernel_launch(void* const* d_in, const int* in_sizes, int n_in,
                              void* d_out, int out_size, void* d_ws, size_t ws_size,
                              hipStream_t stream) {
    const float* x = (const float*)d_in[0];   // 32768 x 512 fp32
    const float* W = (const float*)d_in[1];   // 1024 x 1024 fp32
    const float* b = (const float*)d_in[2];   // 1024 fp32
    float* out = (float*)d_out;               // 32768 x 256 fp32
    __bf16* Bm = (__bf16*)d_ws;               // 256 KiB bf16 W image

    ng_prep<<<dim3(64), dim3(256), 0, stream>>>(W, Bm);
    ng_gemm<<<dim3(M_TOT / ROWS_PER_BLK), dim3(NTH), 0, stream>>>(x, Bm, b, out);
}

// Round 5
// 127.778 us; speedup vs baseline: 1.1803x; 1.1803x over previous
//
#include <hip/hip_runtime.h>
#include <hip/hip_bf16.h>

// out[m,n] = sum_k x[m,k] * W[1023-n,k] + b[1023-n]
// M=32768, N=256, K=512; fp32 in/out; bf16 MFMA.
// Structure: prepass builds swizzled bf16 B-image (2 K-half LDS images, 256 KiB total).
// GEMM: B staged to LDS once per K-half (3 barriers total); A streamed global->VGPR
// fragments with a 2-deep rotating prefetch pinned by sched_barrier(0) per step.

#define M_TOT 32768
#define K_TOT 512
#define N_TOT 256
#define W_LD  1024

#define NTH 512
#define BM 128
#define HALF_B 131072   /* bytes per half-K image: 256 n x 256 k x 2B */

typedef __bf16 bf16x8 __attribute__((ext_vector_type(8)));
typedef float  f32x4  __attribute__((ext_vector_type(4)));

static __device__ __forceinline__ bf16x8 cvt8(f32x4 a, f32x4 b) {
    bf16x8 r;
    r[0] = (__bf16)a[0]; r[1] = (__bf16)a[1]; r[2] = (__bf16)a[2]; r[3] = (__bf16)a[3];
    r[4] = (__bf16)b[0]; r[5] = (__bf16)b[1]; r[6] = (__bf16)b[2]; r[7] = (__bf16)b[3];
    return r;
}

// ---- prepass: swizzled bf16 image of W_sel, exact LDS byte layout per K-half ----
// element (n, k_in_half) at byte  h*HALF_B + n*512 + ((k*2) ^ ((n&7)<<4))
__global__ __launch_bounds__(256)
void ng_prep(const float* __restrict__ W, unsigned char* __restrict__ img)
{
    const int id = blockIdx.x * 256 + threadIdx.x;  // 16384 units: h(2) x n(256) x kg(32)
    const int h  = id >> 13;
    const int n  = (id >> 5) & 255;
    const int kg = id & 31;
    const float* src = W + (long)(1023 - n) * W_LD + h * 256 + kg * 8;
    f32x4 a = *(const f32x4*)src;
    f32x4 b = *(const f32x4*)(src + 4);
    *(bf16x8*)(img + h * HALF_B + n * 512 + ((kg * 16) ^ ((n & 7) << 4))) = cvt8(a, b);
}

#define GLL16(gp_, lp_) __builtin_amdgcn_global_load_lds(                     \
        (const __attribute__((address_space(1))) void*)(gp_),                 \
        (__attribute__((address_space(3))) void*)(lp_), 16, 0, 0)

__global__ __launch_bounds__(NTH, 2)
void ng_gemm(const float* __restrict__ x, const unsigned char* __restrict__ img,
             const float* __restrict__ bias, float* __restrict__ out)
{
    __shared__ __align__(16) unsigned char lds[HALF_B];   // 128 KiB -> 1 block/CU

    const int tid  = threadIdx.x;
    const int lane = tid & 63;
    const int wid  = tid >> 6;
    const int wr   = wid >> 2;   // 0..1 : 64 rows each (4 m-frags)
    const int wc   = wid & 3;    // 0..3 : 64 cols each (4 n-frags)
    const long mBase = (long)blockIdx.x * BM;
    const int r16 = lane & 15;
    const int ko  = lane >> 4;

    // A fragment row pointers (4 m-frags); per-step offset folds into imm offset (S*128B)
    const float* pa[4];
#pragma unroll
    for (int mi = 0; mi < 4; ++mi)
        pa[mi] = x + (mBase + wr * 64 + mi * 16 + r16) * K_TOT + ko * 8;

    // B LDS read bases: per n-frag j, separate even/odd-kk bases so the XOR swizzle
    // folds entirely at compile time (addr = (kk>>1)*128 + base[j][kk&1])
    int bBase[4][2];
#pragma unroll
    for (int j = 0; j < 4; ++j) {
        const int rb = wc * 64 + j * 16 + r16;
        const int sw = (rb & 7) << 4;
        bBase[j][0] = rb * 512 + ((ko * 16) ^ sw);
        bBase[j][1] = rb * 512 + ((64 + ko * 16) ^ sw);
    }

    f32x4 acc[4][4];
#pragma unroll
    for (int mi = 0; mi < 4; ++mi)
#pragma unroll
        for (int ni = 0; ni < 4; ++ni)
            acc[mi][ni] = (f32x4){0.f, 0.f, 0.f, 0.f};

    f32x4  As[3][8];   // rotating 2-deep A prefetch (all indices compile-time)
    bf16x8 Bs[2][4];   // 1-deep B prefetch

#define LOADA(slot_, S_) do {                                                 \
        _Pragma("unroll")                                                     \
        for (int mi_ = 0; mi_ < 4; ++mi_) {                                   \
            As[slot_][2 * mi_ + 0] = *(const f32x4*)(pa[mi_] + (S_) * 32);    \
            As[slot_][2 * mi_ + 1] = *(const f32x4*)(pa[mi_] + (S_) * 32 + 4);\
        }                                                                     \
    } while (0)

#define LOADB(slot_, KK_) do {                                                \
        _Pragma("unroll")                                                     \
        for (int j_ = 0; j_ < 4; ++j_)                                        \
            Bs[slot_][j_] = *(const bf16x8*)(lds + ((KK_) >> 1) * 128         \
                                             + bBase[j_][(KK_) & 1]);         \
    } while (0)

#define MMA(slot_, bslot_) do {                                               \
        bf16x8 a_[4];                                                         \
        _Pragma("unroll")                                                     \
        for (int mi_ = 0; mi_ < 4; ++mi_)                                     \
            a_[mi_] = cvt8(As[slot_][2 * mi_], As[slot_][2 * mi_ + 1]);       \
        _Pragma("unroll")                                                     \
        for (int mi_ = 0; mi_ < 4; ++mi_)                                     \
            _Pragma("unroll")                                                 \
            for (int ni_ = 0; ni_ < 4; ++ni_)                                 \
                acc[mi_][ni_] = __builtin_amdgcn_mfma_f32_16x16x32_bf16(      \
                    a_[mi_], Bs[bslot_][ni_], acc[mi_][ni_], 0, 0, 0);        \
    } while (0)

#define STAGE(h_) do {                                                        \
        const unsigned char* s_ = img + (h_) * HALF_B;                        \
        _Pragma("unroll")                                                     \
        for (int p_ = 0; p_ < 16; ++p_)                                       \
            GLL16(s_ + p_ * 8192 + tid * 16,                                  \
                  lds + p_ * 8192 + wid * 1024);                              \
    } while (0)

#define STEP(S_) do {                                                         \
        if ((S_) + 2 < 16) LOADA(((S_) + 2) % 3, (S_) + 2);                   \
        if (((S_) & 7) != 7) LOADB(((S_) + 1) & 1, ((S_) + 1) & 7);           \
        __builtin_amdgcn_sched_barrier(0);                                    \
        __builtin_amdgcn_s_setprio(1);                                        \
        MMA((S_) % 3, (S_) & 1);                                              \
        __builtin_amdgcn_s_setprio(0);                                        \
        __builtin_amdgcn_sched_barrier(0);                                    \
    } while (0)

    // prologue: A prefetch rides under the 128 KiB B-stage
    LOADA(0, 0);
    LOADA(1, 1);
    STAGE(0);
    __syncthreads();
    LOADB(0, 0);

#pragma unroll
    for (int S = 0; S < 8; ++S) STEP(S);

    __syncthreads();           // all waves done reading half-0 LDS
    STAGE(1);
    __syncthreads();           // half-1 staged
    LOADB(0, 0);

#pragma unroll
    for (int S = 8; S < 16; ++S) STEP(S);

    // ---- epilogue: C/D layout col=lane&15, row=(lane>>4)*4+i ; reversed bias ----
    const int cRow = wr * 64 + (lane >> 4) * 4;
    const int cCol = wc * 64 + (lane & 15);
#pragma unroll
    for (int ni = 0; ni < 4; ++ni) {
        const int gn = cCol + ni * 16;
        const float bv = bias[1023 - gn];
#pragma unroll
        for (int mi = 0; mi < 4; ++mi) {
            float* dst = out + (mBase + cRow + mi * 16) * (long)N_TOT + gn;
#pragma unroll
            for (int i = 0; i < 4; ++i)
                dst[(long)i * N_TOT] = acc[mi][ni][i] + bv;
        }
    }
#undef LOADA
#undef LOADB
#undef MMA
#undef STAGE
#undef STEP
}

extern "C" void kernel_launch(void* const* d_in, const int* in_sizes, int n_in,
                              void* d_out, int out_size, void* d_ws, size_t ws_size,
                              hipStream_t stream) {
    const float* x = (const float*)d_in[0];   // 32768 x 512 fp32
    const float* W = (const float*)d_in[1];   // 1024 x 1024 fp32
    const float* b = (const float*)d_in[2];   // 1024 fp32
    float* out = (float*)d_out;               // 32768 x 256 fp32
    unsigned char* img = (unsigned char*)d_ws; // 256 KiB swizzled bf16 W image

    ng_prep<<<dim3(64), dim3(256), 0, stream>>>(W, img);
    ng_gemm<<<dim3(M_TOT / BM), dim3(NTH), 0, stream>>>(x, img, b, out);
}